// Round 9
// baseline (506.227 us; speedup 1.0000x reference)
//
#include <hip/hip_runtime.h>

// Inputs: floats fp32, ints int32. Outputs fp32 (verified round 7).
// Round 9: k_gemm -> 1-wave blocks, 2 cols/thread (pk-fma), register epilogue;
//          k_attn -> parallel max/denom reductions.

// ---------- helpers ----------
__device__ __forceinline__ float gelu_f(float x) {
    return 0.5f * x * (1.0f + erff(x * 0.70710678118654752440f)); // exact gelu
}
__device__ __forceinline__ float waveReduceSum(float v) {
#pragma unroll
    for (int o = 32; o; o >>= 1) v += __shfl_xor(v, o, 64);
    return v;
}
__device__ __forceinline__ float waveReduceMax(float v) {
#pragma unroll
    for (int o = 32; o; o >>= 1) v = fmaxf(v, __shfl_xor(v, o, 64));
    return v;
}

// ---------- 1. h = layernorm(x, w, b)  (one wave per row) ----------
__global__ void k_ln1(const float* __restrict__ x, const float* __restrict__ w,
                      const float* __restrict__ b, float* __restrict__ h, int N) {
    int row  = (blockIdx.x * blockDim.x + threadIdx.x) >> 6;
    int lane = threadIdx.x & 63;
    if (row >= N) return;
    size_t base = (size_t)row * 128;
    float2 xv = ((const float2*)(x + base))[lane];
    float v0 = xv.x, v1 = xv.y;
    float s  = waveReduceSum(v0 + v1);
    float s2 = waveReduceSum(v0 * v0 + v1 * v1);
    float mu = s * (1.0f / 128.0f);
    float var = s2 * (1.0f / 128.0f) - mu * mu;
    float rstd = 1.0f / sqrtf(var + 1e-5f);
    int d = lane * 2;
    float2 ov;
    ov.x = (v0 - mu) * rstd * w[d]     + b[d];
    ov.y = (v1 - mu) * rstd * w[d + 1] + b[d + 1];
    ((float2*)(h + base))[lane] = ov;
}

// ---------- 2. deg[dst] += 1 ----------
__global__ void k_deg(const int* __restrict__ ei, int* __restrict__ deg, int E) {
    int e = blockIdx.x * blockDim.x + threadIdx.x;
    if (e < E) atomicAdd(&deg[ei[E + e]], 1);    // edge_index row 1 = dst
}

// ---------- 3. scan: chunk sums -> chunk scan -> per-element cursor ----------
__global__ void k_chunksum(const int* __restrict__ deg, int* __restrict__ csum, int N) {
    int i = blockIdx.x * 256 + threadIdx.x;
    int v = (i < N) ? deg[i] : 0;
#pragma unroll
    for (int o = 32; o; o >>= 1) v += __shfl_xor(v, o, 64);
    __shared__ int buf[4];
    int lane = threadIdx.x & 63, wv = threadIdx.x >> 6;
    if (lane == 0) buf[wv] = v;
    __syncthreads();
    if (threadIdx.x == 0) csum[blockIdx.x] = buf[0] + buf[1] + buf[2] + buf[3];
}
__global__ void k_chunkscan(const int* __restrict__ csum, int* __restrict__ coff, int nch) {
    int t = threadIdx.x;
    int v = (t < nch) ? csum[t] : 0;
    __shared__ int sb[256];
    sb[t] = v; __syncthreads();
    for (int o = 1; o < 256; o <<= 1) {
        int a = (t >= o) ? sb[t - o] : 0;
        __syncthreads();
        sb[t] += a;
        __syncthreads();
    }
    coff[t] = sb[t] - v;    // exclusive
}
__global__ void k_cursor(const int* __restrict__ deg, const int* __restrict__ coff,
                         int* __restrict__ cursor, int N) {
    int t = threadIdx.x;
    int i = blockIdx.x * 256 + t;
    int v = (i < N) ? deg[i] : 0;
    __shared__ int sb[256];
    sb[t] = v; __syncthreads();
    for (int o = 1; o < 256; o <<= 1) {
        int a = (t >= o) ? sb[t - o] : 0;
        __syncthreads();
        sb[t] += a;
        __syncthreads();
    }
    if (i < N) cursor[i] = sb[t] - v + coff[blockIdx.x];   // exclusive scan = row start
}

// ---------- 4. CSR scatter (cursor: start -> end) ----------
__global__ void k_scatter(const int* __restrict__ ei, int* __restrict__ cursor,
                          int* __restrict__ nbr, int E) {
    int e = blockIdx.x * blockDim.x + threadIdx.x;
    if (e >= E) return;
    int s = ei[e], d = ei[E + e];
    int pos = atomicAdd(&cursor[d], 1);
    nbr[pos] = s;
}

// ---------- 5. CSR gather + mean (one wave per node; cursor holds END) ----------
__global__ void k_aggcsr(const float* __restrict__ h, const int* __restrict__ cursor,
                         const int* __restrict__ deg, const int* __restrict__ nbr,
                         float* __restrict__ mean, int N) {
    int node = (blockIdx.x * blockDim.x + threadIdx.x) >> 6;
    int lane = threadIdx.x & 63;
    if (node >= N) return;
    int dg = deg[node];
    int st = cursor[node] - dg;          // end - deg = start
    float a0 = 0.f, a1 = 0.f;
    for (int j = 0; j < dg; j++) {
        int s = nbr[st + j];
        float2 v = ((const float2*)(h + (size_t)s * 128))[lane];
        a0 += v.x; a1 += v.y;
    }
    float inv = 1.0f / fmaxf((float)dg, 1.0f);
    float2 ov; ov.x = a0 * inv; ov.y = a1 * inv;
    ((float2*)(mean + (size_t)node * 128))[lane] = ov;
}

// ---------- 6. fused: h2 = mean@W_l + b_l + h@W_r ; LN ; gelu ; gate ----------
// One wave per block; thread l owns output cols 2l, 2l+1 (float2 / pk-fma).
// Epilogue reduces straight from registers (lane l holds cols 2l,2l+1).
// h3 overwrites h in place (all 16 rows staged to LDS before first write).
__global__ void __launch_bounds__(64) k_gemm(
    const float* __restrict__ mean, float* __restrict__ h,
    const float* __restrict__ Wl, const float* __restrict__ bl,
    const float* __restrict__ Wr,
    const float* __restrict__ lnw, const float* __restrict__ lnb,
    const float* __restrict__ gw, const float* __restrict__ gb,
    float* __restrict__ gate, int N) {
    __shared__ float Aln[16][132];   // 132: 16B-aligned rows (528 B)
    __shared__ float Ah[16][132];
    int l = threadIdx.x;             // 0..63
    int row0 = blockIdx.x * 16;
    int c0 = 2 * l;
#pragma unroll
    for (int r = 0; r < 16; r++) {
        int row = row0 + r;
        float2 a = make_float2(0.f, 0.f), c = make_float2(0.f, 0.f);
        if (row < N) {
            a = ((const float2*)(mean + (size_t)row * 128))[l];
            c = ((const float2*)(h    + (size_t)row * 128))[l];
        }
        *(float2*)&Aln[r][c0] = a;
        *(float2*)&Ah[r][c0]  = c;
    }
    __syncthreads();
    float2 acc[16];
    float2 bias = *(const float2*)&bl[c0];
#pragma unroll
    for (int r = 0; r < 16; r++) acc[r] = bias;
    for (int k = 0; k < 128; k += 4) {
        float2 wl0 = *(const float2*)&Wl[(k + 0) * 128 + c0];
        float2 wl1 = *(const float2*)&Wl[(k + 1) * 128 + c0];
        float2 wl2 = *(const float2*)&Wl[(k + 2) * 128 + c0];
        float2 wl3 = *(const float2*)&Wl[(k + 3) * 128 + c0];
        float2 wr0 = *(const float2*)&Wr[(k + 0) * 128 + c0];
        float2 wr1 = *(const float2*)&Wr[(k + 1) * 128 + c0];
        float2 wr2 = *(const float2*)&Wr[(k + 2) * 128 + c0];
        float2 wr3 = *(const float2*)&Wr[(k + 3) * 128 + c0];
#pragma unroll
        for (int r = 0; r < 16; r++) {
            float4 a = *(const float4*)&Aln[r][k];
            float4 c = *(const float4*)&Ah[r][k];
            acc[r].x += a.x * wl0.x + a.y * wl1.x + a.z * wl2.x + a.w * wl3.x
                      + c.x * wr0.x + c.y * wr1.x + c.z * wr2.x + c.w * wr3.x;
            acc[r].y += a.x * wl0.y + a.y * wl1.y + a.z * wl2.y + a.w * wl3.y
                      + c.x * wr0.y + c.y * wr1.y + c.z * wr2.y + c.w * wr3.y;
        }
    }
    // epilogue: LN + gelu + gate, straight from registers
    float2 lw = *(const float2*)&lnw[c0];
    float2 lb = *(const float2*)&lnb[c0];
    float2 gv = *(const float2*)&gw[c0];
    float gbias = gb[0];
#pragma unroll
    for (int r = 0; r < 16; r++) {
        int row = row0 + r;
        if (row >= N) break;
        float v0 = acc[r].x, v1 = acc[r].y;
        float s  = waveReduceSum(v0 + v1);
        float s2 = waveReduceSum(v0 * v0 + v1 * v1);
        float mu = s * (1.f / 128.f);
        float var = s2 * (1.f / 128.f) - mu * mu;
        float rstd = 1.0f / sqrtf(var + 1e-5f);
        float g0 = gelu_f((v0 - mu) * rstd * lw.x + lb.x);
        float g1 = gelu_f((v1 - mu) * rstd * lw.y + lb.y);
        float gp = waveReduceSum(g0 * gv.x + g1 * gv.y);
        ((float2*)(h + (size_t)row * 128))[l] = make_float2(g0, g1);  // h3 in place
        if (l == 0) gate[row] = gp + gbias;
    }
}

// ---------- 7. segment boundaries from sorted batch ----------
__global__ void k_segstart(const int* __restrict__ batch, int* __restrict__ segstart,
                           int N, int G) {
    int i = blockIdx.x * blockDim.x + threadIdx.x;
    if (i >= N) return;
    int b = batch[i];
    if (i == 0) {
        for (int g = 0; g <= b; g++) segstart[g] = 0;
    } else {
        int pb = batch[i - 1];
        for (int g = pb + 1; g <= b; g++) segstart[g] = i;
    }
    if (i == N - 1) {
        for (int g = b + 1; g <= G; g++) segstart[g] = N;
    }
}

// ---------- 8. softmax over segment + weighted pool (one 128-thread block / graph) ----
__global__ void __launch_bounds__(128) k_attn(
    const float* __restrict__ gate, const float* __restrict__ h3,
    const int* __restrict__ segstart,
    float* __restrict__ ge_out, float* __restrict__ attn_out, int G) {
    int g = blockIdx.x, t = threadIdx.x;
    int s0 = segstart[g], s1 = segstart[g + 1];
    if (s1 <= s0) {                      // empty segment -> zeros
        ge_out[(size_t)g * 128 + t] = 0.0f;
        return;
    }
    int lane = t & 63, wv = t >> 6;
    __shared__ float wbuf[2];
    __shared__ float pbuf[128];
    // parallel max
    float m = -3.0e38f;
    for (int i = s0 + t; i < s1; i += 128) m = fmaxf(m, gate[i]);
    m = waveReduceMax(m);
    if (lane == 0) wbuf[wv] = m;
    __syncthreads();
    m = fmaxf(wbuf[0], wbuf[1]);
    __syncthreads();
    // parallel denom
    float dsum = 0.f;
    for (int i = s0 + t; i < s1; i += 128) dsum += expf(gate[i] - m);
    dsum = waveReduceSum(dsum);
    if (lane == 0) wbuf[wv] = dsum;
    __syncthreads();
    float inv = 1.0f / (wbuf[0] + wbuf[1]);
    // weighted pooling, 128-row chunks
    float acc = 0.f;
    for (int base = s0; base < s1; base += 128) {
        int n = min(128, s1 - base);
        __syncthreads();
        if (t < n) {
            float p = expf(gate[base + t] - m) * inv;
            pbuf[t] = p;
            attn_out[base + t] = p;
        }
        __syncthreads();
        for (int j = 0; j < n; j++)
            acc += pbuf[j] * h3[(size_t)(base + j) * 128 + t];
    }
    ge_out[(size_t)g * 128 + t] = acc;
}

// ---------- 9. msg_emb = gelu(text @ msg_W + msg_b)  (one block per graph, LDS text) --
__global__ void __launch_bounds__(128) k_msg(
    const float* __restrict__ text, const float* __restrict__ W,
    const float* __restrict__ bb, float* __restrict__ out, int G) {
    int g = blockIdx.x, t = threadIdx.x;
    __shared__ float txt[768];
    for (int i = t; i < 768; i += 128) txt[i] = text[(size_t)g * 768 + i];
    __syncthreads();
    float acc = bb[t];
    for (int k = 0; k < 768; k += 4) {
        float4 a = *(const float4*)&txt[k];
        acc += a.x * W[(k + 0) * 128 + t] + a.y * W[(k + 1) * 128 + t]
             + a.z * W[(k + 2) * 128 + t] + a.w * W[(k + 3) * 128 + t];
    }
    out[(size_t)g * 128 + t] = gelu_f(acc);
}

// ---------- 10. feat_emb = gelu(features @ feat_W + feat_b) ----------
__global__ void k_feat(const float* __restrict__ feats, const float* __restrict__ W,
                       const float* __restrict__ bb, float* __restrict__ out, int total) {
    int gid = blockIdx.x * blockDim.x + threadIdx.x;
    if (gid >= total) return;
    int g = gid >> 7, o = gid & 127;
    float acc = bb[o];
#pragma unroll
    for (int k = 0; k < 14; k++) acc += feats[g * 14 + k] * W[k * 128 + o];
    out[gid] = gelu_f(acc);
}

// ---------- 11. head: concat -> LN(384) -> logits (one 128-thread block / graph) -----
__global__ void __launch_bounds__(128) k_head(
    const float* __restrict__ ge, const float* __restrict__ me,
    const float* __restrict__ fe, const float* __restrict__ gwt,
    const float* __restrict__ mixw, const float* __restrict__ mixb,
    const float* __restrict__ fc1W, const float* __restrict__ fc1b,
    float* __restrict__ logits, int G) {
    int g = blockIdx.x, t = threadIdx.x;
    __shared__ float rbuf[4];
    float e0 = gwt[0] * ge[(size_t)g * 128 + t];
    float e1 = me[(size_t)g * 128 + t];
    float e2 = fe[(size_t)g * 128 + t];
    float ps = e0 + e1 + e2, ps2 = e0 * e0 + e1 * e1 + e2 * e2;
    int lane = t & 63, w = t >> 6;
    float r1 = waveReduceSum(ps), r2 = waveReduceSum(ps2);
    if (lane == 0) { rbuf[w] = r1; rbuf[2 + w] = r2; }
    __syncthreads();
    float S = rbuf[0] + rbuf[1], S2 = rbuf[2] + rbuf[3];
    float mu = S * (1.f / 384.f);
    float var = S2 * (1.f / 384.f) - mu * mu;
    float rstd = 1.0f / sqrtf(var + 1e-5f);
    float n0 = (e0 - mu) * rstd * mixw[t]       + mixb[t];
    float n1 = (e1 - mu) * rstd * mixw[128 + t] + mixb[128 + t];
    float n2 = (e2 - mu) * rstd * mixw[256 + t] + mixb[256 + t];
    float lp = n0 * fc1W[t] + n1 * fc1W[128 + t] + n2 * fc1W[256 + t];
    __syncthreads();
    float r3 = waveReduceSum(lp);
    if (lane == 0) rbuf[w] = r3;
    __syncthreads();
    if (t == 0) logits[g] = rbuf[0] + rbuf[1] + fc1b[0];
}

// ---------- launch ----------
extern "C" void kernel_launch(void* const* d_in, const int* in_sizes, int n_in,
                              void* d_out, int out_size, void* d_ws, size_t ws_size,
                              hipStream_t stream) {
    const float* x     = (const float*)d_in[0];
    const int*   ei    = (const int*)d_in[1];
    const int*   batch = (const int*)d_in[2];
    const float* text  = (const float*)d_in[4];
    const float* feats = (const float*)d_in[5];
    const float* lnpw  = (const float*)d_in[6];
    const float* lnpb  = (const float*)d_in[7];
    const float* Wl    = (const float*)d_in[8];
    const float* bl    = (const float*)d_in[9];
    const float* Wr    = (const float*)d_in[10];
    const float* lncw  = (const float*)d_in[11];
    const float* lncb  = (const float*)d_in[12];
    const float* gatew = (const float*)d_in[13];
    const float* gateb = (const float*)d_in[14];
    const float* gwt   = (const float*)d_in[15];
    const float* msgW  = (const float*)d_in[16];
    const float* msgb  = (const float*)d_in[17];
    const float* featW = (const float*)d_in[18];
    const float* featb = (const float*)d_in[19];
    const float* mixw  = (const float*)d_in[20];
    const float* mixb  = (const float*)d_in[21];
    const float* fc1W  = (const float*)d_in[22];
    const float* fc1b  = (const float*)d_in[23];

    int N = in_sizes[0] / 128;
    int E = in_sizes[1] / 2;
    int G = in_sizes[4] / 768;

    char* wp = (char*)d_ws;
    auto alloc = [&](size_t bytes) -> char* {
        char* p = wp; wp += (bytes + 255) & ~(size_t)255; return p;
    };
    float* h     = (float*)alloc((size_t)N * 128 * 4);   // h -> h3 in place
    float* mean  = (float*)alloc((size_t)N * 128 * 4);
    float* gate  = (float*)alloc((size_t)N * 4);
    int*   deg   = (int*)alloc((size_t)N * 4);
    int*   cursor= (int*)alloc((size_t)N * 4);
    int*   nbr   = (int*)alloc((size_t)E * 4);
    int*   csum  = (int*)alloc(1024 * 4);
    int*   coff  = (int*)alloc(1024 * 4);
    float* me_ws = (float*)alloc((size_t)G * 128 * 4);
    float* fe_ws = (float*)alloc((size_t)G * 128 * 4);
    int*   segst = (int*)alloc((size_t)(G + 2) * 4);

    // OUTPUTS fp32, flat in return order:
    float* logits_out = (float*)d_out;                 // [G, 1]
    float* ge_out     = logits_out + G;                // [G, 128]
    float* attn_out   = ge_out + (size_t)G * 128;      // [N, 1]

    int totGF = G * 128;
    int nch = (N + 255) / 256;   // 196 <= 256: one chunkscan block suffices

    hipMemsetAsync(deg, 0, (size_t)N * 4, stream);

    k_ln1      <<<(N + 3) / 4,       256, 0, stream>>>(x, lnpw, lnpb, h, N);
    k_deg      <<<(E + 255) / 256,   256, 0, stream>>>(ei, deg, E);
    k_chunksum <<<nch,               256, 0, stream>>>(deg, csum, N);
    k_chunkscan<<<1,                 256, 0, stream>>>(csum, coff, nch);
    k_cursor   <<<nch,               256, 0, stream>>>(deg, coff, cursor, N);
    k_scatter  <<<(E + 255) / 256,   256, 0, stream>>>(ei, cursor, nbr, E);
    k_aggcsr   <<<(N + 3) / 4,       256, 0, stream>>>(h, cursor, deg, nbr, mean, N);
    k_gemm     <<<(N + 15) / 16,      64, 0, stream>>>(mean, h, Wl, bl, Wr, lncw, lncb,
                                                       gatew, gateb, gate, N);
    k_segstart <<<(N + 255) / 256,   256, 0, stream>>>(batch, segst, N, G);
    k_attn     <<<G,                 128, 0, stream>>>(gate, h, segst, ge_out, attn_out, G);
    k_msg      <<<G,                 128, 0, stream>>>(text, msgW, msgb, me_ws, G);
    k_feat     <<<(totGF + 255) / 256, 256, 0, stream>>>(feats, featW, featb, fe_ws, totGF);
    k_head     <<<G,                 128, 0, stream>>>(ge_out, me_ws, fe_ws, gwt,
                                                       mixw, mixb, fc1W, fc1b,
                                                       logits_out, G);
}

// Round 10
// 406.294 us; speedup vs baseline: 1.2460x; 1.2460x over previous
//
#include <hip/hip_runtime.h>

// Inputs: floats fp32, ints int32. Outputs fp32 (verified round 7).
// Round 10: k_gemm back to 128-thr/2-wave (r8 winner) with H2 aliased onto Aln
//           (LDS 25.6->16.9 KB, 6->9 blocks/CU); k_aggcsr gather unrolled x4.

// ---------- helpers ----------
__device__ __forceinline__ float gelu_f(float x) {
    return 0.5f * x * (1.0f + erff(x * 0.70710678118654752440f)); // exact gelu
}
__device__ __forceinline__ float waveReduceSum(float v) {
#pragma unroll
    for (int o = 32; o; o >>= 1) v += __shfl_xor(v, o, 64);
    return v;
}
__device__ __forceinline__ float waveReduceMax(float v) {
#pragma unroll
    for (int o = 32; o; o >>= 1) v = fmaxf(v, __shfl_xor(v, o, 64));
    return v;
}

// ---------- 1. h = layernorm(x, w, b)  (one wave per row) ----------
__global__ void k_ln1(const float* __restrict__ x, const float* __restrict__ w,
                      const float* __restrict__ b, float* __restrict__ h, int N) {
    int row  = (blockIdx.x * blockDim.x + threadIdx.x) >> 6;
    int lane = threadIdx.x & 63;
    if (row >= N) return;
    size_t base = (size_t)row * 128;
    float2 xv = ((const float2*)(x + base))[lane];
    float v0 = xv.x, v1 = xv.y;
    float s  = waveReduceSum(v0 + v1);
    float s2 = waveReduceSum(v0 * v0 + v1 * v1);
    float mu = s * (1.0f / 128.0f);
    float var = s2 * (1.0f / 128.0f) - mu * mu;
    float rstd = 1.0f / sqrtf(var + 1e-5f);
    int d = lane * 2;
    float2 ov;
    ov.x = (v0 - mu) * rstd * w[d]     + b[d];
    ov.y = (v1 - mu) * rstd * w[d + 1] + b[d + 1];
    ((float2*)(h + base))[lane] = ov;
}

// ---------- 2. deg[dst] += 1 ----------
__global__ void k_deg(const int* __restrict__ ei, int* __restrict__ deg, int E) {
    int e = blockIdx.x * blockDim.x + threadIdx.x;
    if (e < E) atomicAdd(&deg[ei[E + e]], 1);    // edge_index row 1 = dst
}

// ---------- 3. scan: chunk sums -> chunk scan -> per-element cursor ----------
__global__ void k_chunksum(const int* __restrict__ deg, int* __restrict__ csum, int N) {
    int i = blockIdx.x * 256 + threadIdx.x;
    int v = (i < N) ? deg[i] : 0;
#pragma unroll
    for (int o = 32; o; o >>= 1) v += __shfl_xor(v, o, 64);
    __shared__ int buf[4];
    int lane = threadIdx.x & 63, wv = threadIdx.x >> 6;
    if (lane == 0) buf[wv] = v;
    __syncthreads();
    if (threadIdx.x == 0) csum[blockIdx.x] = buf[0] + buf[1] + buf[2] + buf[3];
}
__global__ void k_chunkscan(const int* __restrict__ csum, int* __restrict__ coff, int nch) {
    int t = threadIdx.x;
    int v = (t < nch) ? csum[t] : 0;
    __shared__ int sb[256];
    sb[t] = v; __syncthreads();
    for (int o = 1; o < 256; o <<= 1) {
        int a = (t >= o) ? sb[t - o] : 0;
        __syncthreads();
        sb[t] += a;
        __syncthreads();
    }
    coff[t] = sb[t] - v;    // exclusive
}
__global__ void k_cursor(const int* __restrict__ deg, const int* __restrict__ coff,
                         int* __restrict__ cursor, int N) {
    int t = threadIdx.x;
    int i = blockIdx.x * 256 + t;
    int v = (i < N) ? deg[i] : 0;
    __shared__ int sb[256];
    sb[t] = v; __syncthreads();
    for (int o = 1; o < 256; o <<= 1) {
        int a = (t >= o) ? sb[t - o] : 0;
        __syncthreads();
        sb[t] += a;
        __syncthreads();
    }
    if (i < N) cursor[i] = sb[t] - v + coff[blockIdx.x];   // exclusive scan = row start
}

// ---------- 4. CSR scatter (cursor: start -> end) ----------
__global__ void k_scatter(const int* __restrict__ ei, int* __restrict__ cursor,
                          int* __restrict__ nbr, int E) {
    int e = blockIdx.x * blockDim.x + threadIdx.x;
    if (e >= E) return;
    int s = ei[e], d = ei[E + e];
    int pos = atomicAdd(&cursor[d], 1);
    nbr[pos] = s;
}

// ---------- 5. CSR gather + mean (one wave per node; 4-wide load pipelining) ----------
__global__ void k_aggcsr(const float* __restrict__ h, const int* __restrict__ cursor,
                         const int* __restrict__ deg, const int* __restrict__ nbr,
                         float* __restrict__ mean, int N) {
    int node = (blockIdx.x * blockDim.x + threadIdx.x) >> 6;
    int lane = threadIdx.x & 63;
    if (node >= N) return;
    int dg = deg[node];
    int st = cursor[node] - dg;          // end - deg = start
    float a0 = 0.f, a1 = 0.f;
    int j = 0;
    for (; j + 4 <= dg; j += 4) {        // 4 independent row gathers in flight
        int s0 = nbr[st + j],     s1 = nbr[st + j + 1];
        int s2 = nbr[st + j + 2], s3 = nbr[st + j + 3];
        float2 v0 = ((const float2*)(h + (size_t)s0 * 128))[lane];
        float2 v1 = ((const float2*)(h + (size_t)s1 * 128))[lane];
        float2 v2 = ((const float2*)(h + (size_t)s2 * 128))[lane];
        float2 v3 = ((const float2*)(h + (size_t)s3 * 128))[lane];
        a0 += v0.x + v1.x + v2.x + v3.x;
        a1 += v0.y + v1.y + v2.y + v3.y;
    }
    for (; j < dg; j++) {
        int s = nbr[st + j];
        float2 v = ((const float2*)(h + (size_t)s * 128))[lane];
        a0 += v.x; a1 += v.y;
    }
    float inv = 1.0f / fmaxf((float)dg, 1.0f);
    float2 ov; ov.x = a0 * inv; ov.y = a1 * inv;
    ((float2*)(mean + (size_t)node * 128))[lane] = ov;
}

// ---------- 6. fused: h2 = mean@W_l + b_l + h@W_r ; LN ; gelu ; gate ----------
// 128 threads (2 waves), 16 rows/block, thread t owns col t.
// H2 is aliased onto Aln (dead after the k-loop) -> LDS 16.9 KB, 9 blocks/CU.
// h3 overwrites h in place (all rows staged to LDS before first write).
__global__ void __launch_bounds__(128) k_gemm(
    const float* __restrict__ mean, float* __restrict__ h,
    const float* __restrict__ Wl, const float* __restrict__ bl,
    const float* __restrict__ Wr,
    const float* __restrict__ lnw, const float* __restrict__ lnb,
    const float* __restrict__ gw, const float* __restrict__ gb,
    float* __restrict__ gate, int N) {
    __shared__ float Aln[16][132];   // +4 pad; doubles as H2 after the k-loop
    __shared__ float Ah[16][132];
    int t = threadIdx.x;
    int row0 = blockIdx.x * 16;
#pragma unroll
    for (int r = 0; r < 16; r++) {
        int row = row0 + r;
        float a = 0.f, c = 0.f;
        if (row < N) { a = mean[(size_t)row * 128 + t]; c = h[(size_t)row * 128 + t]; }
        Aln[r][t] = a; Ah[r][t] = c;
    }
    __syncthreads();
    float acc[16];
    float bias = bl[t];
#pragma unroll
    for (int r = 0; r < 16; r++) acc[r] = bias;
    for (int k = 0; k < 128; k += 4) {
        float wl0 = Wl[(k + 0) * 128 + t], wl1 = Wl[(k + 1) * 128 + t];
        float wl2 = Wl[(k + 2) * 128 + t], wl3 = Wl[(k + 3) * 128 + t];
        float wr0 = Wr[(k + 0) * 128 + t], wr1 = Wr[(k + 1) * 128 + t];
        float wr2 = Wr[(k + 2) * 128 + t], wr3 = Wr[(k + 3) * 128 + t];
#pragma unroll
        for (int r = 0; r < 16; r++) {
            float4 a = *(const float4*)&Aln[r][k];
            float4 c = *(const float4*)&Ah[r][k];
            acc[r] += a.x * wl0 + a.y * wl1 + a.z * wl2 + a.w * wl3
                    + c.x * wr0 + c.y * wr1 + c.z * wr2 + c.w * wr3;
        }
    }
    __syncthreads();                 // all k-loop reads of Aln done -> safe to overwrite
#pragma unroll
    for (int r = 0; r < 16; r++) Aln[r][t] = acc[r];   // H2 into Aln
    __syncthreads();
    int wv = t >> 6, lane = t & 63;
    int d = lane * 2;
    float lw0 = lnw[d], lw1 = lnw[d + 1];
    float lb0 = lnb[d], lb1 = lnb[d + 1];
    float gw0 = gw[d],  gw1 = gw[d + 1];
    float gbias = gb[0];
    for (int r = wv; r < 16; r += 2) {     // wave-uniform row loop, no block sync inside
        int row = row0 + r;
        if (row >= N) break;
        float v0 = Aln[r][d], v1 = Aln[r][d + 1];
        float s  = waveReduceSum(v0 + v1);
        float s2 = waveReduceSum(v0 * v0 + v1 * v1);
        float mu = s * (1.f / 128.f);
        float var = s2 * (1.f / 128.f) - mu * mu;
        float rstd = 1.0f / sqrtf(var + 1e-5f);
        float g0 = gelu_f((v0 - mu) * rstd * lw0 + lb0);
        float g1 = gelu_f((v1 - mu) * rstd * lw1 + lb1);
        float gp = waveReduceSum(g0 * gw0 + g1 * gw1);
        ((float2*)(h + (size_t)row * 128))[lane] = make_float2(g0, g1);  // h3 in place
        if (lane == 0) gate[row] = gp + gbias;
    }
}

// ---------- 7. segment boundaries from sorted batch ----------
__global__ void k_segstart(const int* __restrict__ batch, int* __restrict__ segstart,
                           int N, int G) {
    int i = blockIdx.x * blockDim.x + threadIdx.x;
    if (i >= N) return;
    int b = batch[i];
    if (i == 0) {
        for (int g = 0; g <= b; g++) segstart[g] = 0;
    } else {
        int pb = batch[i - 1];
        for (int g = pb + 1; g <= b; g++) segstart[g] = i;
    }
    if (i == N - 1) {
        for (int g = b + 1; g <= G; g++) segstart[g] = N;
    }
}

// ---------- 8. softmax over segment + weighted pool (one 128-thread block / graph) ----
__global__ void __launch_bounds__(128) k_attn(
    const float* __restrict__ gate, const float* __restrict__ h3,
    const int* __restrict__ segstart,
    float* __restrict__ ge_out, float* __restrict__ attn_out, int G) {
    int g = blockIdx.x, t = threadIdx.x;
    int s0 = segstart[g], s1 = segstart[g + 1];
    if (s1 <= s0) {                      // empty segment -> zeros
        ge_out[(size_t)g * 128 + t] = 0.0f;
        return;
    }
    int lane = t & 63, wv = t >> 6;
    __shared__ float wbuf[2];
    __shared__ float pbuf[128];
    // parallel max
    float m = -3.0e38f;
    for (int i = s0 + t; i < s1; i += 128) m = fmaxf(m, gate[i]);
    m = waveReduceMax(m);
    if (lane == 0) wbuf[wv] = m;
    __syncthreads();
    m = fmaxf(wbuf[0], wbuf[1]);
    __syncthreads();
    // parallel denom
    float dsum = 0.f;
    for (int i = s0 + t; i < s1; i += 128) dsum += expf(gate[i] - m);
    dsum = waveReduceSum(dsum);
    if (lane == 0) wbuf[wv] = dsum;
    __syncthreads();
    float inv = 1.0f / (wbuf[0] + wbuf[1]);
    // weighted pooling, 128-row chunks
    float acc = 0.f;
    for (int base = s0; base < s1; base += 128) {
        int n = min(128, s1 - base);
        __syncthreads();
        if (t < n) {
            float p = expf(gate[base + t] - m) * inv;
            pbuf[t] = p;
            attn_out[base + t] = p;
        }
        __syncthreads();
        for (int j = 0; j < n; j++)
            acc += pbuf[j] * h3[(size_t)(base + j) * 128 + t];
    }
    ge_out[(size_t)g * 128 + t] = acc;
}

// ---------- 9. msg_emb = gelu(text @ msg_W + msg_b)  (one block per graph, LDS text) --
__global__ void __launch_bounds__(128) k_msg(
    const float* __restrict__ text, const float* __restrict__ W,
    const float* __restrict__ bb, float* __restrict__ out, int G) {
    int g = blockIdx.x, t = threadIdx.x;
    __shared__ float txt[768];
    for (int i = t; i < 768; i += 128) txt[i] = text[(size_t)g * 768 + i];
    __syncthreads();
    float acc = bb[t];
    for (int k = 0; k < 768; k += 4) {
        float4 a = *(const float4*)&txt[k];
        acc += a.x * W[(k + 0) * 128 + t] + a.y * W[(k + 1) * 128 + t]
             + a.z * W[(k + 2) * 128 + t] + a.w * W[(k + 3) * 128 + t];
    }
    out[(size_t)g * 128 + t] = gelu_f(acc);
}

// ---------- 10. feat_emb = gelu(features @ feat_W + feat_b) ----------
__global__ void k_feat(const float* __restrict__ feats, const float* __restrict__ W,
                       const float* __restrict__ bb, float* __restrict__ out, int total) {
    int gid = blockIdx.x * blockDim.x + threadIdx.x;
    if (gid >= total) return;
    int g = gid >> 7, o = gid & 127;
    float acc = bb[o];
#pragma unroll
    for (int k = 0; k < 14; k++) acc += feats[g * 14 + k] * W[k * 128 + o];
    out[gid] = gelu_f(acc);
}

// ---------- 11. head: concat -> LN(384) -> logits (one 128-thread block / graph) -----
__global__ void __launch_bounds__(128) k_head(
    const float* __restrict__ ge, const float* __restrict__ me,
    const float* __restrict__ fe, const float* __restrict__ gwt,
    const float* __restrict__ mixw, const float* __restrict__ mixb,
    const float* __restrict__ fc1W, const float* __restrict__ fc1b,
    float* __restrict__ logits, int G) {
    int g = blockIdx.x, t = threadIdx.x;
    __shared__ float rbuf[4];
    float e0 = gwt[0] * ge[(size_t)g * 128 + t];
    float e1 = me[(size_t)g * 128 + t];
    float e2 = fe[(size_t)g * 128 + t];
    float ps = e0 + e1 + e2, ps2 = e0 * e0 + e1 * e1 + e2 * e2;
    int lane = t & 63, w = t >> 6;
    float r1 = waveReduceSum(ps), r2 = waveReduceSum(ps2);
    if (lane == 0) { rbuf[w] = r1; rbuf[2 + w] = r2; }
    __syncthreads();
    float S = rbuf[0] + rbuf[1], S2 = rbuf[2] + rbuf[3];
    float mu = S * (1.f / 384.f);
    float var = S2 * (1.f / 384.f) - mu * mu;
    float rstd = 1.0f / sqrtf(var + 1e-5f);
    float n0 = (e0 - mu) * rstd * mixw[t]       + mixb[t];
    float n1 = (e1 - mu) * rstd * mixw[128 + t] + mixb[128 + t];
    float n2 = (e2 - mu) * rstd * mixw[256 + t] + mixb[256 + t];
    float lp = n0 * fc1W[t] + n1 * fc1W[128 + t] + n2 * fc1W[256 + t];
    __syncthreads();
    float r3 = waveReduceSum(lp);
    if (lane == 0) rbuf[w] = r3;
    __syncthreads();
    if (t == 0) logits[g] = rbuf[0] + rbuf[1] + fc1b[0];
}

// ---------- launch ----------
extern "C" void kernel_launch(void* const* d_in, const int* in_sizes, int n_in,
                              void* d_out, int out_size, void* d_ws, size_t ws_size,
                              hipStream_t stream) {
    const float* x     = (const float*)d_in[0];
    const int*   ei    = (const int*)d_in[1];
    const int*   batch = (const int*)d_in[2];
    const float* text  = (const float*)d_in[4];
    const float* feats = (const float*)d_in[5];
    const float* lnpw  = (const float*)d_in[6];
    const float* lnpb  = (const float*)d_in[7];
    const float* Wl    = (const float*)d_in[8];
    const float* bl    = (const float*)d_in[9];
    const float* Wr    = (const float*)d_in[10];
    const float* lncw  = (const float*)d_in[11];
    const float* lncb  = (const float*)d_in[12];
    const float* gatew = (const float*)d_in[13];
    const float* gateb = (const float*)d_in[14];
    const float* gwt   = (const float*)d_in[15];
    const float* msgW  = (const float*)d_in[16];
    const float* msgb  = (const float*)d_in[17];
    const float* featW = (const float*)d_in[18];
    const float* featb = (const float*)d_in[19];
    const float* mixw  = (const float*)d_in[20];
    const float* mixb  = (const float*)d_in[21];
    const float* fc1W  = (const float*)d_in[22];
    const float* fc1b  = (const float*)d_in[23];

    int N = in_sizes[0] / 128;
    int E = in_sizes[1] / 2;
    int G = in_sizes[4] / 768;

    char* wp = (char*)d_ws;
    auto alloc = [&](size_t bytes) -> char* {
        char* p = wp; wp += (bytes + 255) & ~(size_t)255; return p;
    };
    float* h     = (float*)alloc((size_t)N * 128 * 4);   // h -> h3 in place
    float* mean  = (float*)alloc((size_t)N * 128 * 4);
    float* gate  = (float*)alloc((size_t)N * 4);
    int*   deg   = (int*)alloc((size_t)N * 4);
    int*   cursor= (int*)alloc((size_t)N * 4);
    int*   nbr   = (int*)alloc((size_t)E * 4);
    int*   csum  = (int*)alloc(1024 * 4);
    int*   coff  = (int*)alloc(1024 * 4);
    float* me_ws = (float*)alloc((size_t)G * 128 * 4);
    float* fe_ws = (float*)alloc((size_t)G * 128 * 4);
    int*   segst = (int*)alloc((size_t)(G + 2) * 4);

    // OUTPUTS fp32, flat in return order:
    float* logits_out = (float*)d_out;                 // [G, 1]
    float* ge_out     = logits_out + G;                // [G, 128]
    float* attn_out   = ge_out + (size_t)G * 128;      // [N, 1]

    int totGF = G * 128;
    int nch = (N + 255) / 256;   // 196 <= 256: one chunkscan block suffices

    hipMemsetAsync(deg, 0, (size_t)N * 4, stream);

    k_ln1      <<<(N + 3) / 4,       256, 0, stream>>>(x, lnpw, lnpb, h, N);
    k_deg      <<<(E + 255) / 256,   256, 0, stream>>>(ei, deg, E);
    k_chunksum <<<nch,               256, 0, stream>>>(deg, csum, N);
    k_chunkscan<<<1,                 256, 0, stream>>>(csum, coff, nch);
    k_cursor   <<<nch,               256, 0, stream>>>(deg, coff, cursor, N);
    k_scatter  <<<(E + 255) / 256,   256, 0, stream>>>(ei, cursor, nbr, E);
    k_aggcsr   <<<(N + 3) / 4,       256, 0, stream>>>(h, cursor, deg, nbr, mean, N);
    k_gemm     <<<(N + 15) / 16,     128, 0, stream>>>(mean, h, Wl, bl, Wr, lncw, lncb,
                                                       gatew, gateb, gate, N);
    k_segstart <<<(N + 255) / 256,   256, 0, stream>>>(batch, segst, N, G);
    k_attn     <<<G,                 128, 0, stream>>>(gate, h, segst, ge_out, attn_out, G);
    k_msg      <<<G,                 128, 0, stream>>>(text, msgW, msgb, me_ws, G);
    k_feat     <<<(totGF + 255) / 256, 256, 0, stream>>>(feats, featW, featb, fe_ws, totGF);
    k_head     <<<G,                 128, 0, stream>>>(ge_out, me_ws, fe_ws, gwt,
                                                       mixw, mixb, fc1W, fc1b,
                                                       logits_out, G);
}